// Round 6
// baseline (2805.925 us; speedup 1.0000x reference)
//
#include <hip/hip_runtime.h>
#include <hip/hip_bf16.h>
#include <math.h>

// GraphCast processor, round 6:
// - GEMM rewritten register-direct: NO LDS, NO barriers, NO global_load_lds.
//   Each MFMA fragment is a per-lane contiguous 16B granule of row-major
//   bf16 A (hi/lo) and B^T, loaded straight to VGPRs with global_load_dwordx4.
//   R3-R5 showed the all-DMA staging path is insensitive to any pipeline
//   schedule (105 us, MfmaUtil 3.8%, all pipes idle); R1's reg-path GEMM was
//   <=75 us. Waves are now fully independent; latency hidden by TLP/MLP.
// - Everything else unchanged from round 5.

#define NNODES 40962
#define NEDGES 163848
#define NLAYERS 6
#define MPAD 41088   // 321*128, zero-padded rows so A loads need no predication

typedef __attribute__((ext_vector_type(8))) short short8;
typedef __attribute__((ext_vector_type(4))) float f32x4;
typedef unsigned short ushort_t;

// truncation split: v = hi + lo with hi,lo bf16
__device__ __forceinline__ void bsplit(float v, ushort_t& h, ushort_t& l) {
    unsigned int u = __float_as_uint(v);
    h = (ushort_t)(u >> 16);
    float hf = __uint_as_float(u & 0xFFFF0000u);
    l = (ushort_t)(__float_as_uint(v - hf) >> 16);
}

// ---------------- weight prep: transpose fp32 [R][C] -> bf16(RNE) [C][R] ----------------
__global__ __launch_bounds__(256) void wprep_kernel(
    const float* __restrict__ src, ushort_t* __restrict__ dst,
    int R, int C, size_t src_lstride, size_t src_hstride, int halves)
{
    __shared__ float t[32][33];
    const int b = blockIdx.z;
    src += (size_t)(b / halves) * src_lstride + (size_t)(b % halves) * src_hstride;
    dst += (size_t)b * R * C;
    const int tx = threadIdx.x & 31, ty = threadIdx.x >> 5;
    const int c0 = blockIdx.x * 32, r0 = blockIdx.y * 32;
    #pragma unroll
    for (int i = 0; i < 4; ++i)
        t[ty + 8 * i][tx] = src[(size_t)(r0 + ty + 8 * i) * C + c0 + tx];
    __syncthreads();
    #pragma unroll
    for (int i = 0; i < 4; ++i) {
        unsigned int u = __float_as_uint(t[tx][ty + 8 * i]);
        ushort_t h = (ushort_t)((u + 0x7FFFu + ((u >> 16) & 1u)) >> 16); // RNE
        dst[(size_t)(c0 + ty + 8 * i) * R + r0 + tx] = h;
    }
}

// ---------------- initial x split: fp32 -> bf16 hi/lo ----------------
__global__ __launch_bounds__(256) void split_kernel(
    const float* __restrict__ x, ushort_t* __restrict__ xh,
    ushort_t* __restrict__ xl, int n4)
{
    int idx = blockIdx.x * 256 + threadIdx.x;
    if (idx >= n4) return;
    float4 v = ((const float4*)x)[idx];
    ushort4 oh, ol;
    bsplit(v.x, oh.x, ol.x); bsplit(v.y, oh.y, ol.y);
    bsplit(v.z, oh.z, ol.z); bsplit(v.w, oh.w, ol.w);
    ((ushort4*)xh)[idx] = oh;
    ((ushort4*)xl)[idx] = ol;
}

// ---------------- MFMA GEMM (register-direct, no LDS, no barriers) ----------------
// C[M x (grid.y*128)] = (A1 K-concat A2) @ B (+bias) (+resid), A bf16 hi+lo.
// A*: bf16 [MPAD][256] row-major (concat at k=256). BT: bf16 [Ncols][K].
// Fragment granule = per-lane contiguous 16B: A row m0+wm*64+i*16+(lane&15),
// k-offset (lane>>4)*8. Loaded directly global->VGPR each K-step; all waves
// independent, compiler/TLP hides latency.
__global__ __launch_bounds__(256) void gemm_mfma(
    const ushort_t* __restrict__ A1h, const ushort_t* __restrict__ A1l,
    const ushort_t* __restrict__ A2h, const ushort_t* __restrict__ A2l,
    const ushort_t* __restrict__ BT,
    const float* __restrict__ bias, const float* __restrict__ resid,
    float* __restrict__ C, ushort_t* __restrict__ Ch, ushort_t* __restrict__ Cl,
    int M, int K, int ldC)
{
    const int tid = threadIdx.x;
    const int wave = tid >> 6;
    const int lane = tid & 63;
    const int m0 = blockIdx.x * 128;
    const int n0 = blockIdx.y * 128;
    const int wm = wave >> 1, wn = wave & 1;
    const int fm = lane & 15, quad = lane >> 4;
    const int ko = quad * 8;   // this lane's k-offset within the 32-wide K-slice

    // per-lane element offsets (loop-invariant)
    size_t aOff[4], bOff[4];
    #pragma unroll
    for (int i = 0; i < 4; ++i)
        aOff[i] = (size_t)(m0 + wm * 64 + i * 16 + fm) * 256 + ko;
    #pragma unroll
    for (int j = 0; j < 4; ++j)
        bOff[j] = (size_t)(n0 + wn * 64 + j * 16 + fm) * (size_t)K + ko;

    f32x4 acc[4][4];
    #pragma unroll
    for (int i = 0; i < 4; ++i)
        #pragma unroll
        for (int j = 0; j < 4; ++j)
            acc[i][j] = (f32x4){0.f, 0.f, 0.f, 0.f};

    const int nkt = K >> 5;
    for (int kt = 0; kt < nkt; ++kt) {
        const int k0 = kt << 5;
        const ushort_t* Ah_g = A1h;
        const ushort_t* Al_g = A1l;
        int kb = k0;
        if (k0 >= 256) { Ah_g = A2h; Al_g = A2l; kb = k0 - 256; }

        short8 afh[4], afl[4], bf[4];
        #pragma unroll
        for (int i = 0; i < 4; ++i) {
            afh[i] = *(const short8*)(Ah_g + aOff[i] + kb);
            afl[i] = *(const short8*)(Al_g + aOff[i] + kb);
        }
        #pragma unroll
        for (int j = 0; j < 4; ++j)
            bf[j] = *(const short8*)(BT + bOff[j] + k0);

        #pragma unroll
        for (int i = 0; i < 4; ++i)
            #pragma unroll
            for (int j = 0; j < 4; ++j) {
                acc[i][j] = __builtin_amdgcn_mfma_f32_16x16x32_bf16(afl[i], bf[j], acc[i][j], 0, 0, 0);
                acc[i][j] = __builtin_amdgcn_mfma_f32_16x16x32_bf16(afh[i], bf[j], acc[i][j], 0, 0, 0);
            }
    }

    // epilogue: C/D layout col=lane&15, row=quad*4+reg
    #pragma unroll
    for (int j = 0; j < 4; ++j) {
        const int gc = n0 + wn * 64 + j * 16 + fm;
        const float bj = bias ? bias[gc] : 0.f;
        #pragma unroll
        for (int i = 0; i < 4; ++i) {
            #pragma unroll
            for (int r = 0; r < 4; ++r) {
                const int gr = m0 + wm * 64 + i * 16 + quad * 4 + r;
                if (gr < M) {
                    float v = acc[i][j][r] + bj;
                    if (resid) v += resid[(size_t)gr * ldC + gc];
                    C[(size_t)gr * ldC + gc] = v;
                    if (Ch) {
                        ushort_t hs, ls;
                        bsplit(v, hs, ls);
                        Ch[(size_t)gr * 256 + gc] = hs;
                        Cl[(size_t)gr * 256 + gc] = ls;
                    }
                }
            }
        }
    }
}

__device__ __forceinline__ float wave_sum(float v) {
    #pragma unroll
    for (int o = 32; o > 0; o >>= 1) v += __shfl_xor(v, o);
    return v;
}

// ---------------- CSR build (once per launch) ----------------
__global__ __launch_bounds__(256) void count_kernel(
    const int* __restrict__ dst, int* __restrict__ deg, int E)
{
    int e = blockIdx.x * 256 + threadIdx.x;
    if (e < E) atomicAdd(&deg[dst[e]], 1);
}

__global__ __launch_bounds__(1024) void scan_kernel(
    const int* __restrict__ deg, int* __restrict__ rowptr, int n)
{
    __shared__ int wsum[16];
    __shared__ int carry_s;
    const int tid = threadIdx.x;
    const int lane = tid & 63, wave = tid >> 6;
    if (tid == 0) carry_s = 0;
    __syncthreads();

    for (int base = 0; base < n; base += 1024) {
        int i = base + tid;
        int v = (i < n) ? deg[i] : 0;
        int x = v;
        #pragma unroll
        for (int o = 1; o < 64; o <<= 1) {
            int t = __shfl_up(x, o);
            if (lane >= o) x += t;
        }
        if (lane == 63) wsum[wave] = x;
        __syncthreads();
        if (wave == 0 && lane < 16) {
            int w = wsum[lane];
            #pragma unroll
            for (int o = 1; o < 16; o <<= 1) {
                int t = __shfl_up(w, o);
                if (lane >= o) w += t;
            }
            wsum[lane] = w;
        }
        __syncthreads();
        int wave_off = (wave == 0) ? 0 : wsum[wave - 1];
        int incl = x + wave_off + carry_s;
        if (i < n) rowptr[i] = incl - v;
        __syncthreads();
        if (tid == 0) carry_s += wsum[15];
        __syncthreads();
    }
    if (tid == 0) rowptr[n] = carry_s;
}

__global__ __launch_bounds__(256) void scatter_kernel(
    const int* __restrict__ dst, int* __restrict__ cursor,
    int* __restrict__ esorted, int E)
{
    int e = blockIdx.x * 256 + threadIdx.x;
    if (e < E) {
        int p = atomicAdd(&cursor[dst[e]], 1);
        esorted[p] = e;
    }
}

// ---------------- fused per-node message + aggregate ----------------
__global__ __launch_bounds__(256) void node_agg_kernel(
    const float* __restrict__ P,      // [N,512]
    const int* __restrict__ src,
    const float* __restrict__ attr,   // [E,4]
    const float* __restrict__ W3,     // [4,256]
    const float* __restrict__ be, const float* __restrict__ g1, const float* __restrict__ b1,
    const int* __restrict__ rowptr, const int* __restrict__ esorted,
    ushort_t* __restrict__ aggh, ushort_t* __restrict__ aggl, int N)
{
    const int wave = threadIdx.x >> 6;
    const int lane = threadIdx.x & 63;
    const int n = blockIdx.x * 4 + wave;
    if (n >= N) return;
    const int c0 = lane * 4;

    float4 p1 = *(const float4*)(P + (size_t)n * 512 + c0);
    const float* p1p = (const float*)&p1;

    float w30[4], w31[4], w32[4], w33[4], bev[4], g1v[4], b1v[4];
    #pragma unroll
    for (int i = 0; i < 4; ++i) {
        const int c = c0 + i;
        w30[i] = W3[c]; w31[i] = W3[256 + c]; w32[i] = W3[512 + c]; w33[i] = W3[768 + c];
        bev[i] = be[c]; g1v[i] = g1[c]; b1v[i] = b1[c];
    }

    float acc[4] = {0.f, 0.f, 0.f, 0.f};
    const int beg = rowptr[n];
    const int end = rowptr[n + 1];

    if (beg < end) {
        int iB0 = (beg + 1 < end) ? beg + 1 : beg;
        int eA = esorted[beg], eB = esorted[iB0];
        int sA = src[eA], sB = src[eB];
        float4 psA = *(const float4*)(P + (size_t)sA * 512 + 256 + c0);
        float4 avA = *(const float4*)(attr + (size_t)eA * 4);
        float4 psB = *(const float4*)(P + (size_t)sB * 512 + 256 + c0);
        float4 avB = *(const float4*)(attr + (size_t)eB * 4);
        bool vB = (beg + 1 < end);

        for (int i = beg; i < end; i += 2) {
            int jA = (i + 2 < end) ? i + 2 : i;
            int jB = (i + 3 < end) ? i + 3 : jA;
            int eA2 = esorted[jA], eB2 = esorted[jB];
            int sA2 = src[eA2], sB2 = src[eB2];
            float4 psA2 = *(const float4*)(P + (size_t)sA2 * 512 + 256 + c0);
            float4 avA2 = *(const float4*)(attr + (size_t)eA2 * 4);
            float4 psB2 = *(const float4*)(P + (size_t)sB2 * 512 + 256 + c0);
            float4 avB2 = *(const float4*)(attr + (size_t)eB2 * 4);

            const float* pA = (const float*)&psA;
            const float* pB = (const float*)&psB;
            float hA[4], hB[4];
            #pragma unroll
            for (int j = 0; j < 4; ++j) {
                float wA = avA.x * w30[j] + avA.y * w31[j] + avA.z * w32[j] + avA.w * w33[j];
                hA[j] = p1p[j] + pA[j] + wA + bev[j];
                float wB = avB.x * w30[j] + avB.y * w31[j] + avB.z * w32[j] + avB.w * w33[j];
                hB[j] = p1p[j] + pB[j] + wB + bev[j];
            }

            float s1A = hA[0] + hA[1] + hA[2] + hA[3];
            float s2A = hA[0]*hA[0] + hA[1]*hA[1] + hA[2]*hA[2] + hA[3]*hA[3];
            float s1B = hB[0] + hB[1] + hB[2] + hB[3];
            float s2B = hB[0]*hB[0] + hB[1]*hB[1] + hB[2]*hB[2] + hB[3]*hB[3];
            #pragma unroll
            for (int o = 32; o > 0; o >>= 1) {
                s1A += __shfl_xor(s1A, o); s2A += __shfl_xor(s2A, o);
                s1B += __shfl_xor(s1B, o); s2B += __shfl_xor(s2B, o);
            }
            const float mA = s1A * (1.0f / 256.0f);
            const float vrA = fmaxf(s2A * (1.0f / 256.0f) - mA * mA, 0.f);
            const float rA = rsqrtf(vrA + 1e-5f);
            const float mB = s1B * (1.0f / 256.0f);
            const float vrB = fmaxf(s2B * (1.0f / 256.0f) - mB * mB, 0.f);
            const float rB = rsqrtf(vrB + 1e-5f);
            const float addB = vB ? 1.f : 0.f;

            #pragma unroll
            for (int j = 0; j < 4; ++j) {
                float yA = (hA[j] - mA) * rA * g1v[j] + b1v[j];
                acc[j] += yA / (1.0f + __expf(-yA));
                float yB = (hB[j] - mB) * rB * g1v[j] + b1v[j];
                acc[j] += addB * (yB / (1.0f + __expf(-yB)));
            }

            psA = psA2; avA = avA2; psB = psB2; avB = avB2;
            vB = (i + 3 < end);
        }
    }

    ushort4 oh, ol;
    bsplit(acc[0], oh.x, ol.x); bsplit(acc[1], oh.y, ol.y);
    bsplit(acc[2], oh.z, ol.z); bsplit(acc[3], oh.w, ol.w);
    *(ushort4*)(aggh + (size_t)n * 256 + c0) = oh;
    *(ushort4*)(aggl + (size_t)n * 256 + c0) = ol;
}

// LayerNorm + SiLU over rows of u [N,256]; writes bf16 hi/lo; one wave per row.
__global__ __launch_bounds__(256) void ln_silu_kernel(
    const float* __restrict__ u, const float* __restrict__ g, const float* __restrict__ b,
    ushort_t* __restrict__ sh, ushort_t* __restrict__ sl, int N)
{
    const int wave = threadIdx.x >> 6;
    const int lane = threadIdx.x & 63;
    const int r = blockIdx.x * 4 + wave;
    if (r >= N) return;

    float4 hv = *(const float4*)(u + (size_t)r * 256 + lane * 4);
    float h[4] = {hv.x, hv.y, hv.z, hv.w};

    float s1 = h[0] + h[1] + h[2] + h[3];
    float s2 = h[0]*h[0] + h[1]*h[1] + h[2]*h[2] + h[3]*h[3];
    #pragma unroll
    for (int o = 32; o > 0; o >>= 1) {
        s1 += __shfl_xor(s1, o); s2 += __shfl_xor(s2, o);
    }
    const float mean = s1 * (1.0f / 256.0f);
    const float var = fmaxf(s2 * (1.0f / 256.0f) - mean * mean, 0.f);
    const float rstd = rsqrtf(var + 1e-5f);

    ushort4 oh, ol;
    #pragma unroll
    for (int i = 0; i < 4; ++i) {
        const int c = lane * 4 + i;
        float y = (h[i] - mean) * rstd * g[c] + b[c];
        h[i] = y / (1.0f + __expf(-y));
    }
    bsplit(h[0], oh.x, ol.x); bsplit(h[1], oh.y, ol.y);
    bsplit(h[2], oh.z, ol.z); bsplit(h[3], oh.w, ol.w);
    *(ushort4*)(sh + (size_t)r * 256 + lane * 4) = oh;
    *(ushort4*)(sl + (size_t)r * 256 + lane * 4) = ol;
}

extern "C" void kernel_launch(void* const* d_in, const int* in_sizes, int n_in,
                              void* d_out, int out_size, void* d_ws, size_t ws_size,
                              hipStream_t stream) {
    const float* mesh   = (const float*)d_in[0];
    const int*   eidx   = (const int*)  d_in[1];
    const float* eattr  = (const float*)d_in[2];
    const float* We_w   = (const float*)d_in[3];
    const float* We_b   = (const float*)d_in[4];
    const float* ln1_g  = (const float*)d_in[5];
    const float* ln1_b  = (const float*)d_in[6];
    const float* Wn1_w  = (const float*)d_in[7];
    const float* Wn1_b  = (const float*)d_in[8];
    const float* ln2_g  = (const float*)d_in[9];
    const float* ln2_b  = (const float*)d_in[10];
    const float* Wn2_w  = (const float*)d_in[11];
    const float* Wn2_b  = (const float*)d_in[12];

    const int N = NNODES, E = NEDGES;

    float* x = (float*)d_out;                   // [N,256]
    float* P = (float*)d_ws;                    // [N,512]
    float* u = P;                               // [N,256] aliases P
    int*   deg     = (int*)(P + (size_t)N * 512);
    int*   rowptr  = deg + N;
    int*   cursor  = rowptr + (N + 1);
    int*   esorted = cursor + N;                // E
    uintptr_t wp = (uintptr_t)(esorted + E);
    wp = (wp + 63) & ~(uintptr_t)63;
    ushort_t* BTe  = (ushort_t*)wp;                        // [6][512][256]
    ushort_t* BTn1 = BTe  + (size_t)6 * 512 * 256;         // [6][256][512]
    ushort_t* BTn2 = BTn1 + (size_t)6 * 256 * 512;         // [6][256][256]
    ushort_t* xh   = BTn2 + (size_t)6 * 256 * 256;         // [MPAD][256]
    ushort_t* xl   = xh + (size_t)MPAD * 256;
    ushort_t* sh   = xl + (size_t)MPAD * 256;              // agg-split, then u-split
    ushort_t* sl   = sh + (size_t)MPAD * 256;

    const int* src = eidx;
    const int* dst = eidx + E;

    hipMemcpyAsync(x, mesh, (size_t)N * 256 * sizeof(float),
                   hipMemcpyDeviceToDevice, stream);

    // zero the padded rows of the bf16 A-buffers (rows N..MPAD)
    const size_t padoff = (size_t)N * 256;
    const size_t padbytes = (size_t)(MPAD - N) * 256 * sizeof(ushort_t);
    hipMemsetAsync(xh + padoff, 0, padbytes, stream);
    hipMemsetAsync(xl + padoff, 0, padbytes, stream);
    hipMemsetAsync(sh + padoff, 0, padbytes, stream);
    hipMemsetAsync(sl + padoff, 0, padbytes, stream);

    // initial x hi/lo split
    const int n4 = N * 64;  // N*256/4
    split_kernel<<<(n4 + 255) / 256, 256, 0, stream>>>(mesh, xh, xl, n4);

    // ---- weight prep: bf16 [N][K] transposes ----
    wprep_kernel<<<dim3(8, 8, 12), 256, 0, stream>>>(
        We_w, BTe, 256, 256, (size_t)516 * 256, (size_t)256 * 256, 2);
    wprep_kernel<<<dim3(8, 16, 6), 256, 0, stream>>>(
        Wn1_w, BTn1, 512, 256, (size_t)512 * 256, 0, 1);
    wprep_kernel<<<dim3(8, 8, 6), 256, 0, stream>>>(
        Wn2_w, BTn2, 256, 256, (size_t)256 * 256, 0, 1);

    // ---- CSR build ----
    hipMemsetAsync(deg, 0, (size_t)N * sizeof(int), stream);
    count_kernel<<<(E + 255) / 256, 256, 0, stream>>>(dst, deg, E);
    scan_kernel<<<1, 1024, 0, stream>>>(deg, rowptr, N);
    hipMemcpyAsync(cursor, rowptr, (size_t)N * sizeof(int),
                   hipMemcpyDeviceToDevice, stream);
    scatter_kernel<<<(E + 255) / 256, 256, 0, stream>>>(dst, cursor, esorted, E);

    const int mblocks = MPAD / 128;        // 321
    const int node_blocks = (N + 3) / 4;

    for (int l = 0; l < NLAYERS; ++l) {
        const float* W3  = We_w + (size_t)l * 516 * 256 + (size_t)512 * 256;
        const float* be  = We_b  + (size_t)l * 256;
        const float* g1  = ln1_g + (size_t)l * 256;
        const float* b1  = ln1_b + (size_t)l * 256;
        const float* bn1 = Wn1_b + (size_t)l * 256;
        const float* g2  = ln2_g + (size_t)l * 256;
        const float* b2  = ln2_b + (size_t)l * 256;
        const float* bn2 = Wn2_b + (size_t)l * 256;
        const ushort_t* bte  = BTe  + (size_t)l * 512 * 256;
        const ushort_t* btn1 = BTn1 + (size_t)l * 256 * 512;
        const ushort_t* btn2 = BTn2 + (size_t)l * 256 * 256;

        // P = x @ [W1|W2]  -> [N,512]
        gemm_mfma<<<dim3(mblocks, 4), 256, 0, stream>>>(
            xh, xl, nullptr, nullptr, bte, nullptr, nullptr,
            P, nullptr, nullptr, N, 256, 512);
        // agg[n] = sum over incident edges of silu(LN(h)) -> bf16 hi/lo
        node_agg_kernel<<<node_blocks, 256, 0, stream>>>(
            P, src, eattr, W3, be, g1, b1, rowptr, esorted, sh, sl, N);
        // u = [x | agg] @ Wn1 + bn1   (u aliases P)
        gemm_mfma<<<dim3(mblocks, 2), 256, 0, stream>>>(
            xh, xl, sh, sl, btn1, bn1, nullptr,
            u, nullptr, nullptr, N, 512, 256);
        // u = silu(LN(u)) -> bf16 hi/lo (overwrites agg split; agg is dead)
        ln_silu_kernel<<<node_blocks, 256, 0, stream>>>(u, g2, b2, sh, sl, N);
        // x = x + u @ Wn2 + bn2; epilogue also writes xh/xl for next layer
        gemm_mfma<<<dim3(mblocks, 2), 256, 0, stream>>>(
            sh, sl, nullptr, nullptr, btn2, bn2, x,
            x, (l < NLAYERS - 1) ? xh : nullptr, (l < NLAYERS - 1) ? xl : nullptr,
            N, 256, 256);
    }
}

// Round 7
// 1737.290 us; speedup vs baseline: 1.6151x; 1.6151x over previous
//
#include <hip/hip_runtime.h>
#include <hip/hip_bf16.h>
#include <math.h>

// GraphCast processor, round 7:
// - GEMM staging ladder measured: R1 reg-staged(A)+DMA(B) <=75us; all-DMA
//   103-110us regardless of schedule; reg-direct fragments 147-155us.
//   => Rebuild GEMM as fully reg-staged LDS (the R1 mechanism) fed by the
//   pre-split bf16 buffers (no VALU split), with the validated involution
//   swizzle applied at ds_write (conflict-free ds_read_b128), double-buffered,
//   one barrier per K-step, loads(t+1) issued before MFMA(t) so HBM/L2
//   latency hides under compute. No inline asm; compiler manages waitcnts.
// - node_agg / ln_silu / producers unchanged from round 5.

#define NNODES 40962
#define NEDGES 163848
#define NLAYERS 6
#define MPAD 41088   // 321*128, zero-padded rows so A loads need no predication

typedef __attribute__((ext_vector_type(8))) short short8;
typedef __attribute__((ext_vector_type(4))) float f32x4;
typedef unsigned short ushort_t;

// truncation split: v = hi + lo with hi,lo bf16
__device__ __forceinline__ void bsplit(float v, ushort_t& h, ushort_t& l) {
    unsigned int u = __float_as_uint(v);
    h = (ushort_t)(u >> 16);
    float hf = __uint_as_float(u & 0xFFFF0000u);
    l = (ushort_t)(__float_as_uint(v - hf) >> 16);
}

// ---------------- weight prep: transpose fp32 [R][C] -> bf16(RNE) [C][R] ----------------
__global__ __launch_bounds__(256) void wprep_kernel(
    const float* __restrict__ src, ushort_t* __restrict__ dst,
    int R, int C, size_t src_lstride, size_t src_hstride, int halves)
{
    __shared__ float t[32][33];
    const int b = blockIdx.z;
    src += (size_t)(b / halves) * src_lstride + (size_t)(b % halves) * src_hstride;
    dst += (size_t)b * R * C;
    const int tx = threadIdx.x & 31, ty = threadIdx.x >> 5;
    const int c0 = blockIdx.x * 32, r0 = blockIdx.y * 32;
    #pragma unroll
    for (int i = 0; i < 4; ++i)
        t[ty + 8 * i][tx] = src[(size_t)(r0 + ty + 8 * i) * C + c0 + tx];
    __syncthreads();
    #pragma unroll
    for (int i = 0; i < 4; ++i) {
        unsigned int u = __float_as_uint(t[tx][ty + 8 * i]);
        ushort_t h = (ushort_t)((u + 0x7FFFu + ((u >> 16) & 1u)) >> 16); // RNE
        dst[(size_t)(c0 + ty + 8 * i) * R + r0 + tx] = h;
    }
}

// ---------------- initial x split: fp32 -> bf16 hi/lo ----------------
__global__ __launch_bounds__(256) void split_kernel(
    const float* __restrict__ x, ushort_t* __restrict__ xh,
    ushort_t* __restrict__ xl, int n4)
{
    int idx = blockIdx.x * 256 + threadIdx.x;
    if (idx >= n4) return;
    float4 v = ((const float4*)x)[idx];
    ushort4 oh, ol;
    bsplit(v.x, oh.x, ol.x); bsplit(v.y, oh.y, ol.y);
    bsplit(v.z, oh.z, ol.z); bsplit(v.w, oh.w, ol.w);
    ((ushort4*)xh)[idx] = oh;
    ((ushort4*)xl)[idx] = ol;
}

// ---------------- MFMA GEMM (reg-staged LDS, double-buffered, 1 barrier/step) --------
// C[M x (grid.y*128)] = (A1 K-concat A2) @ B (+bias) (+resid), A bf16 hi+lo.
// A*: bf16 [MPAD][256] row-major (concat at k=256). BT: bf16 [Ncols][K].
// Staging: thread t loads 32B coalesced bf16 for row=t>>1, k-half=(t&1)*16,
// ds_writes the two 16B granules (row,q) at swizzled slot q^((row>>1)&3).
// Fragment ds_read_b128 applies the same involution -> conflict-free
// (validated R4/R5: SQ_LDS_BANK_CONFLICT=0, absmax identical).
__global__ __launch_bounds__(256) void gemm_mfma(
    const ushort_t* __restrict__ A1h, const ushort_t* __restrict__ A1l,
    const ushort_t* __restrict__ A2h, const ushort_t* __restrict__ A2l,
    const ushort_t* __restrict__ BT,
    const float* __restrict__ bias, const float* __restrict__ resid,
    float* __restrict__ C, ushort_t* __restrict__ Ch, ushort_t* __restrict__ Cl,
    int M, int K, int ldC)
{
    // [2 buffers][128 rows][32 shorts] each 8 KB -> 48 KB total
    __shared__ __align__(16) short AhS[2 * 4096];
    __shared__ __align__(16) short AlS[2 * 4096];
    __shared__ __align__(16) short BsS[2 * 4096];

    const int tid = threadIdx.x;
    const int wave = tid >> 6;
    const int lane = tid & 63;
    const int m0 = blockIdx.x * 128;
    const int n0 = blockIdx.y * 128;
    const int wm = wave >> 1, wn = wave & 1;
    const int fm = lane & 15, quad = lane >> 4;

    // staging map: thread -> (row = tid>>1, k-half = (tid&1)*16 elems)
    const int srow = tid >> 1;
    const int shalf = (tid & 1) << 4;
    const int sw = (srow >> 1) & 3;
    const int q0 = (tid & 1) * 2;
    const int slot0 = srow * 64 + (((q0    ) ^ sw) << 4);  // byte offsets
    const int slot1 = srow * 64 + (((q0 + 1) ^ sw) << 4);
    const size_t aRowOff = (size_t)(m0 + srow) * 256 + shalf;
    const size_t bRowOff = (size_t)(n0 + srow) * (size_t)K + shalf;

    // fragment read swizzle: granule (row,quad) lives at byte row*64 + sq16
    const int sq16 = ((quad ^ ((fm >> 1) & 3)) << 4);

    f32x4 acc[4][4];
    #pragma unroll
    for (int i = 0; i < 4; ++i)
        #pragma unroll
        for (int j = 0; j < 4; ++j)
            acc[i][j] = (f32x4){0.f, 0.f, 0.f, 0.f};

    const int nkt = K >> 5;

    // coalesced 32B global loads of this thread's granules for K-tile kt
    auto loadg = [&](int kt, short8& ah0, short8& ah1, short8& al0, short8& al1,
                     short8& b0, short8& b1) {
        const int k0 = kt << 5;
        const ushort_t* Ah_g = A1h;
        const ushort_t* Al_g = A1l;
        int kb = k0;
        if (k0 >= 256) { Ah_g = A2h; Al_g = A2l; kb = k0 - 256; }
        const ushort_t* pa = Ah_g + aRowOff + kb;
        const ushort_t* pl = Al_g + aRowOff + kb;
        const ushort_t* pb = BT + bRowOff + k0;
        ah0 = *(const short8*)pa;       ah1 = *(const short8*)(pa + 8);
        al0 = *(const short8*)pl;       al1 = *(const short8*)(pl + 8);
        b0  = *(const short8*)pb;       b1  = *(const short8*)(pb + 8);
    };
    // swizzled ds_writes into buffer `buf`
    auto storeg = [&](int buf, short8 ah0, short8 ah1, short8 al0, short8 al1,
                      short8 b0, short8 b1) {
        char* bAh = (char*)AhS + buf * 8192;
        char* bAl = (char*)AlS + buf * 8192;
        char* bB  = (char*)BsS + buf * 8192;
        *(short8*)(bAh + slot0) = ah0;  *(short8*)(bAh + slot1) = ah1;
        *(short8*)(bAl + slot0) = al0;  *(short8*)(bAl + slot1) = al1;
        *(short8*)(bB  + slot0) = b0;   *(short8*)(bB  + slot1) = b1;
    };

    {   // prologue: tile 0 into buf 0
        short8 ah0, ah1, al0, al1, b0, b1;
        loadg(0, ah0, ah1, al0, al1, b0, b1);
        storeg(0, ah0, ah1, al0, al1, b0, b1);
    }
    __syncthreads();

    for (int kt = 0; kt < nkt; ++kt) {
        const int cur = kt & 1;
        const bool more = (kt + 1 < nkt);
        short8 nah0, nah1, nal0, nal1, nb0, nb1;
        if (more) loadg(kt + 1, nah0, nah1, nal0, nal1, nb0, nb1);  // in flight

        const char* bAh = (const char*)AhS + cur * 8192;
        const char* bAl = (const char*)AlS + cur * 8192;
        const char* bB  = (const char*)BsS + cur * 8192;

        short8 afh[4], afl[4], bf[4];
        #pragma unroll
        for (int i = 0; i < 4; ++i) {
            const int r = wm * 64 + i * 16 + fm;
            afh[i] = *(const short8*)(bAh + (r << 6) + sq16);
            afl[i] = *(const short8*)(bAl + (r << 6) + sq16);
        }
        #pragma unroll
        for (int j = 0; j < 4; ++j) {
            const int r = wn * 64 + j * 16 + fm;
            bf[j] = *(const short8*)(bB + (r << 6) + sq16);
        }
        #pragma unroll
        for (int i = 0; i < 4; ++i)
            #pragma unroll
            for (int j = 0; j < 4; ++j) {
                acc[i][j] = __builtin_amdgcn_mfma_f32_16x16x32_bf16(afl[i], bf[j], acc[i][j], 0, 0, 0);
                acc[i][j] = __builtin_amdgcn_mfma_f32_16x16x32_bf16(afh[i], bf[j], acc[i][j], 0, 0, 0);
            }

        // ds_write next tile into the other buffer (safe: all waves finished
        // reading it before the barrier that ended iteration kt-1)
        if (more) storeg(cur ^ 1, nah0, nah1, nal0, nal1, nb0, nb1);
        __syncthreads();
    }

    // epilogue: C/D layout col=lane&15, row=quad*4+reg
    #pragma unroll
    for (int j = 0; j < 4; ++j) {
        const int gc = n0 + wn * 64 + j * 16 + fm;
        const float bj = bias ? bias[gc] : 0.f;
        #pragma unroll
        for (int i = 0; i < 4; ++i) {
            #pragma unroll
            for (int r = 0; r < 4; ++r) {
                const int gr = m0 + wm * 64 + i * 16 + quad * 4 + r;
                if (gr < M) {
                    float v = acc[i][j][r] + bj;
                    if (resid) v += resid[(size_t)gr * ldC + gc];
                    C[(size_t)gr * ldC + gc] = v;
                    if (Ch) {
                        ushort_t hs, ls;
                        bsplit(v, hs, ls);
                        Ch[(size_t)gr * 256 + gc] = hs;
                        Cl[(size_t)gr * 256 + gc] = ls;
                    }
                }
            }
        }
    }
}

__device__ __forceinline__ float wave_sum(float v) {
    #pragma unroll
    for (int o = 32; o > 0; o >>= 1) v += __shfl_xor(v, o);
    return v;
}

// ---------------- CSR build (once per launch) ----------------
__global__ __launch_bounds__(256) void count_kernel(
    const int* __restrict__ dst, int* __restrict__ deg, int E)
{
    int e = blockIdx.x * 256 + threadIdx.x;
    if (e < E) atomicAdd(&deg[dst[e]], 1);
}

__global__ __launch_bounds__(1024) void scan_kernel(
    const int* __restrict__ deg, int* __restrict__ rowptr, int n)
{
    __shared__ int wsum[16];
    __shared__ int carry_s;
    const int tid = threadIdx.x;
    const int lane = tid & 63, wave = tid >> 6;
    if (tid == 0) carry_s = 0;
    __syncthreads();

    for (int base = 0; base < n; base += 1024) {
        int i = base + tid;
        int v = (i < n) ? deg[i] : 0;
        int x = v;
        #pragma unroll
        for (int o = 1; o < 64; o <<= 1) {
            int t = __shfl_up(x, o);
            if (lane >= o) x += t;
        }
        if (lane == 63) wsum[wave] = x;
        __syncthreads();
        if (wave == 0 && lane < 16) {
            int w = wsum[lane];
            #pragma unroll
            for (int o = 1; o < 16; o <<= 1) {
                int t = __shfl_up(w, o);
                if (lane >= o) w += t;
            }
            wsum[lane] = w;
        }
        __syncthreads();
        int wave_off = (wave == 0) ? 0 : wsum[wave - 1];
        int incl = x + wave_off + carry_s;
        if (i < n) rowptr[i] = incl - v;
        __syncthreads();
        if (tid == 0) carry_s += wsum[15];
        __syncthreads();
    }
    if (tid == 0) rowptr[n] = carry_s;
}

__global__ __launch_bounds__(256) void scatter_kernel(
    const int* __restrict__ dst, int* __restrict__ cursor,
    int* __restrict__ esorted, int E)
{
    int e = blockIdx.x * 256 + threadIdx.x;
    if (e < E) {
        int p = atomicAdd(&cursor[dst[e]], 1);
        esorted[p] = e;
    }
}

// ---------------- fused per-node message + aggregate ----------------
__global__ __launch_bounds__(256) void node_agg_kernel(
    const float* __restrict__ P,      // [N,512]
    const int* __restrict__ src,
    const float* __restrict__ attr,   // [E,4]
    const float* __restrict__ W3,     // [4,256]
    const float* __restrict__ be, const float* __restrict__ g1, const float* __restrict__ b1,
    const int* __restrict__ rowptr, const int* __restrict__ esorted,
    ushort_t* __restrict__ aggh, ushort_t* __restrict__ aggl, int N)
{
    const int wave = threadIdx.x >> 6;
    const int lane = threadIdx.x & 63;
    const int n = blockIdx.x * 4 + wave;
    if (n >= N) return;
    const int c0 = lane * 4;

    float4 p1 = *(const float4*)(P + (size_t)n * 512 + c0);
    const float* p1p = (const float*)&p1;

    float w30[4], w31[4], w32[4], w33[4], bev[4], g1v[4], b1v[4];
    #pragma unroll
    for (int i = 0; i < 4; ++i) {
        const int c = c0 + i;
        w30[i] = W3[c]; w31[i] = W3[256 + c]; w32[i] = W3[512 + c]; w33[i] = W3[768 + c];
        bev[i] = be[c]; g1v[i] = g1[c]; b1v[i] = b1[c];
    }

    float acc[4] = {0.f, 0.f, 0.f, 0.f};
    const int beg = rowptr[n];
    const int end = rowptr[n + 1];

    if (beg < end) {
        int iB0 = (beg + 1 < end) ? beg + 1 : beg;
        int eA = esorted[beg], eB = esorted[iB0];
        int sA = src[eA], sB = src[eB];
        float4 psA = *(const float4*)(P + (size_t)sA * 512 + 256 + c0);
        float4 avA = *(const float4*)(attr + (size_t)eA * 4);
        float4 psB = *(const float4*)(P + (size_t)sB * 512 + 256 + c0);
        float4 avB = *(const float4*)(attr + (size_t)eB * 4);
        bool vB = (beg + 1 < end);

        for (int i = beg; i < end; i += 2) {
            int jA = (i + 2 < end) ? i + 2 : i;
            int jB = (i + 3 < end) ? i + 3 : jA;
            int eA2 = esorted[jA], eB2 = esorted[jB];
            int sA2 = src[eA2], sB2 = src[eB2];
            float4 psA2 = *(const float4*)(P + (size_t)sA2 * 512 + 256 + c0);
            float4 avA2 = *(const float4*)(attr + (size_t)eA2 * 4);
            float4 psB2 = *(const float4*)(P + (size_t)sB2 * 512 + 256 + c0);
            float4 avB2 = *(const float4*)(attr + (size_t)eB2 * 4);

            const float* pA = (const float*)&psA;
            const float* pB = (const float*)&psB;
            float hA[4], hB[4];
            #pragma unroll
            for (int j = 0; j < 4; ++j) {
                float wA = avA.x * w30[j] + avA.y * w31[j] + avA.z * w32[j] + avA.w * w33[j];
                hA[j] = p1p[j] + pA[j] + wA + bev[j];
                float wB = avB.x * w30[j] + avB.y * w31[j] + avB.z * w32[j] + avB.w * w33[j];
                hB[j] = p1p[j] + pB[j] + wB + bev[j];
            }

            float s1A = hA[0] + hA[1] + hA[2] + hA[3];
            float s2A = hA[0]*hA[0] + hA[1]*hA[1] + hA[2]*hA[2] + hA[3]*hA[3];
            float s1B = hB[0] + hB[1] + hB[2] + hB[3];
            float s2B = hB[0]*hB[0] + hB[1]*hB[1] + hB[2]*hB[2] + hB[3]*hB[3];
            #pragma unroll
            for (int o = 32; o > 0; o >>= 1) {
                s1A += __shfl_xor(s1A, o); s2A += __shfl_xor(s2A, o);
                s1B += __shfl_xor(s1B, o); s2B += __shfl_xor(s2B, o);
            }
            const float mA = s1A * (1.0f / 256.0f);
            const float vrA = fmaxf(s2A * (1.0f / 256.0f) - mA * mA, 0.f);
            const float rA = rsqrtf(vrA + 1e-5f);
            const float mB = s1B * (1.0f / 256.0f);
            const float vrB = fmaxf(s2B * (1.0f / 256.0f) - mB * mB, 0.f);
            const float rB = rsqrtf(vrB + 1e-5f);
            const float addB = vB ? 1.f : 0.f;

            #pragma unroll
            for (int j = 0; j < 4; ++j) {
                float yA = (hA[j] - mA) * rA * g1v[j] + b1v[j];
                acc[j] += yA / (1.0f + __expf(-yA));
                float yB = (hB[j] - mB) * rB * g1v[j] + b1v[j];
                acc[j] += addB * (yB / (1.0f + __expf(-yB)));
            }

            psA = psA2; avA = avA2; psB = psB2; avB = avB2;
            vB = (i + 3 < end);
        }
    }

    ushort4 oh, ol;
    bsplit(acc[0], oh.x, ol.x); bsplit(acc[1], oh.y, ol.y);
    bsplit(acc[2], oh.z, ol.z); bsplit(acc[3], oh.w, ol.w);
    *(ushort4*)(aggh + (size_t)n * 256 + c0) = oh;
    *(ushort4*)(aggl + (size_t)n * 256 + c0) = ol;
}

// LayerNorm + SiLU over rows of u [N,256]; writes bf16 hi/lo; one wave per row.
__global__ __launch_bounds__(256) void ln_silu_kernel(
    const float* __restrict__ u, const float* __restrict__ g, const float* __restrict__ b,
    ushort_t* __restrict__ sh, ushort_t* __restrict__ sl, int N)
{
    const int wave = threadIdx.x >> 6;
    const int lane = threadIdx.x & 63;
    const int r = blockIdx.x * 4 + wave;
    if (r >= N) return;

    float4 hv = *(const float4*)(u + (size_t)r * 256 + lane * 4);
    float h[4] = {hv.x, hv.y, hv.z, hv.w};

    float s1 = h[0] + h[1] + h[2] + h[3];
    float s2 = h[0]*h[0] + h[1]*h[1] + h[2]*h[2] + h[3]*h[3];
    #pragma unroll
    for (int o = 32; o > 0; o >>= 1) {
        s1 += __shfl_xor(s1, o); s2 += __shfl_xor(s2, o);
    }
    const float mean = s1 * (1.0f / 256.0f);
    const float var = fmaxf(s2 * (1.0f / 256.0f) - mean * mean, 0.f);
    const float rstd = rsqrtf(var + 1e-5f);

    ushort4 oh, ol;
    #pragma unroll
    for (int i = 0; i < 4; ++i) {
        const int c = lane * 4 + i;
        float y = (h[i] - mean) * rstd * g[c] + b[c];
        h[i] = y / (1.0f + __expf(-y));
    }
    bsplit(h[0], oh.x, ol.x); bsplit(h[1], oh.y, ol.y);
    bsplit(h[2], oh.z, ol.z); bsplit(h[3], oh.w, ol.w);
    *(ushort4*)(sh + (size_t)r * 256 + lane * 4) = oh;
    *(ushort4*)(sl + (size_t)r * 256 + lane * 4) = ol;
}

extern "C" void kernel_launch(void* const* d_in, const int* in_sizes, int n_in,
                              void* d_out, int out_size, void* d_ws, size_t ws_size,
                              hipStream_t stream) {
    const float* mesh   = (const float*)d_in[0];
    const int*   eidx   = (const int*)  d_in[1];
    const float* eattr  = (const float*)d_in[2];
    const float* We_w   = (const float*)d_in[3];
    const float* We_b   = (const float*)d_in[4];
    const float* ln1_g  = (const float*)d_in[5];
    const float* ln1_b  = (const float*)d_in[6];
    const float* Wn1_w  = (const float*)d_in[7];
    const float* Wn1_b  = (const float*)d_in[8];
    const float* ln2_g  = (const float*)d_in[9];
    const float* ln2_b  = (const float*)d_in[10];
    const float* Wn2_w  = (const float*)d_in[11];
    const float* Wn2_b  = (const float*)d_in[12];

    const int N = NNODES, E = NEDGES;

    float* x = (float*)d_out;                   // [N,256]
    float* P = (float*)d_ws;                    // [N,512]
    float* u = P;                               // [N,256] aliases P
    int*   deg     = (int*)(P + (size_t)N * 512);
    int*   rowptr  = deg + N;
    int*   cursor  = rowptr + (N + 1);
    int*   esorted = cursor + N;                // E
    uintptr_t wp = (uintptr_t)(esorted + E);
    wp = (wp + 63) & ~(uintptr_t)63;
    ushort_t* BTe  = (ushort_t*)wp;                        // [6][512][256]
    ushort_t* BTn1 = BTe  + (size_t)6 * 512 * 256;         // [6][256][512]
    ushort_t* BTn2 = BTn1 + (size_t)6 * 256 * 512;         // [6][256][256]
    ushort_t* xh   = BTn2 + (size_t)6 * 256 * 256;         // [MPAD][256]
    ushort_t* xl   = xh + (size_t)MPAD * 256;
    ushort_t* sh   = xl + (size_t)MPAD * 256;              // agg-split, then u-split
    ushort_t* sl   = sh + (size_t)MPAD * 256;

    const int* src = eidx;
    const int* dst = eidx + E;

    hipMemcpyAsync(x, mesh, (size_t)N * 256 * sizeof(float),
                   hipMemcpyDeviceToDevice, stream);

    // zero the padded rows of the bf16 A-buffers (rows N..MPAD)
    const size_t padoff = (size_t)N * 256;
    const size_t padbytes = (size_t)(MPAD - N) * 256 * sizeof(ushort_t);
    hipMemsetAsync(xh + padoff, 0, padbytes, stream);
    hipMemsetAsync(xl + padoff, 0, padbytes, stream);
    hipMemsetAsync(sh + padoff, 0, padbytes, stream);
    hipMemsetAsync(sl + padoff, 0, padbytes, stream);

    // initial x hi/lo split
    const int n4 = N * 64;  // N*256/4
    split_kernel<<<(n4 + 255) / 256, 256, 0, stream>>>(mesh, xh, xl, n4);

    // ---- weight prep: bf16 [N][K] transposes ----
    wprep_kernel<<<dim3(8, 8, 12), 256, 0, stream>>>(
        We_w, BTe, 256, 256, (size_t)516 * 256, (size_t)256 * 256, 2);
    wprep_kernel<<<dim3(8, 16, 6), 256, 0, stream>>>(
        Wn1_w, BTn1, 512, 256, (size_t)512 * 256, 0, 1);
    wprep_kernel<<<dim3(8, 8, 6), 256, 0, stream>>>(
        Wn2_w, BTn2, 256, 256, (size_t)256 * 256, 0, 1);

    // ---- CSR build ----
    hipMemsetAsync(deg, 0, (size_t)N * sizeof(int), stream);
    count_kernel<<<(E + 255) / 256, 256, 0, stream>>>(dst, deg, E);
    scan_kernel<<<1, 1024, 0, stream>>>(deg, rowptr, N);
    hipMemcpyAsync(cursor, rowptr, (size_t)N * sizeof(int),
                   hipMemcpyDeviceToDevice, stream);
    scatter_kernel<<<(E + 255) / 256, 256, 0, stream>>>(dst, cursor, esorted, E);

    const int mblocks = MPAD / 128;        // 321
    const int node_blocks = (N + 3) / 4;

    for (int l = 0; l < NLAYERS; ++l) {
        const float* W3  = We_w + (size_t)l * 516 * 256 + (size_t)512 * 256;
        const float* be  = We_b  + (size_t)l * 256;
        const float* g1  = ln1_g + (size_t)l * 256;
        const float* b1  = ln1_b + (size_t)l * 256;
        const float* bn1 = Wn1_b + (size_t)l * 256;
        const float* g2  = ln2_g + (size_t)l * 256;
        const float* b2  = ln2_b + (size_t)l * 256;
        const float* bn2 = Wn2_b + (size_t)l * 256;
        const ushort_t* bte  = BTe  + (size_t)l * 512 * 256;
        const ushort_t* btn1 = BTn1 + (size_t)l * 256 * 512;
        const ushort_t* btn2 = BTn2 + (size_t)l * 256 * 256;

        // P = x @ [W1|W2]  -> [N,512]
        gemm_mfma<<<dim3(mblocks, 4), 256, 0, stream>>>(
            xh, xl, nullptr, nullptr, bte, nullptr, nullptr,
            P, nullptr, nullptr, N, 256, 512);
        // agg[n] = sum over incident edges of silu(LN(h)) -> bf16 hi/lo
        node_agg_kernel<<<node_blocks, 256, 0, stream>>>(
            P, src, eattr, W3, be, g1, b1, rowptr, esorted, sh, sl, N);
        // u = [x | agg] @ Wn1 + bn1   (u aliases P)
        gemm_mfma<<<dim3(mblocks, 2), 256, 0, stream>>>(
            xh, xl, sh, sl, btn1, bn1, nullptr,
            u, nullptr, nullptr, N, 512, 256);
        // u = silu(LN(u)) -> bf16 hi/lo (overwrites agg split; agg is dead)
        ln_silu_kernel<<<node_blocks, 256, 0, stream>>>(u, g2, b2, sh, sl, N);
        // x = x + u @ Wn2 + bn2; epilogue also writes xh/xl for next layer
        gemm_mfma<<<dim3(mblocks, 2), 256, 0, stream>>>(
            sh, sl, nullptr, nullptr, btn2, bn2, x,
            x, (l < NLAYERS - 1) ? xh : nullptr, (l < NLAYERS - 1) ? xl : nullptr,
            N, 256, 256);
    }
}